// Round 2
// baseline (12537.135 us; speedup 1.0000x reference)
//
#include <hip/hip_runtime.h>

// Problem constants
#define BB 16
#define SS 2048
#define DD 256
#define ND4 1024   // 4*D
#define PRD 16     // R-buffer slot depth (residual stream)
#define PGD 8      // GX-buffer slot depth (gate pre-activations)
#define HLP 4      // helper WGs per layer

typedef __attribute__((ext_vector_type(8))) _Float16 half8;
typedef __attribute__((ext_vector_type(4))) float f32x4;
typedef __attribute__((ext_vector_type(4))) unsigned int u32x4;
typedef unsigned long long u64;
union H8 { half8 v; unsigned int u[4]; uint4 q; };
union U4 { u32x4 v; unsigned int u[4]; };

__device__ __forceinline__ u64 aload(const u64* p) {
    return __hip_atomic_load(p, __ATOMIC_RELAXED, __HIP_MEMORY_SCOPE_AGENT);
}
__device__ __forceinline__ void astore(u64* p, u64 v) {
    __hip_atomic_store(p, v, __ATOMIC_RELAXED, __HIP_MEMORY_SCOPE_AGENT);
}
// fast path: plain store (write-through L1 -> lands in XCD-local L2)
__device__ __forceinline__ void wgstore(u64* p, u64 v) {
    __hip_atomic_store(p, v, __ATOMIC_RELAXED, __HIP_MEMORY_SCOPE_WORKGROUP);
}
__device__ __forceinline__ unsigned pload(const unsigned* p) {
    return __hip_atomic_load(p, __ATOMIC_RELAXED, __HIP_MEMORY_SCOPE_AGENT);
}
__device__ __forceinline__ void pstore(unsigned* p, unsigned v) {
    __hip_atomic_store(p, v, __ATOMIC_RELAXED, __HIP_MEMORY_SCOPE_AGENT);
}
__device__ __forceinline__ int aflag(int* p) {
    return __hip_atomic_load(p, __ATOMIC_RELAXED, __HIP_MEMORY_SCOPE_AGENT);
}
__device__ __forceinline__ void sflag(int* p) {
    __hip_atomic_store(p, 1, __ATOMIC_RELAXED, __HIP_MEMORY_SCOPE_AGENT);
}
__device__ __forceinline__ unsigned short f16b(float x) {
    union { _Float16 h; unsigned short u; } c; c.h = (_Float16)x; return c.u;
}
// spin guard with backoff for cross-layer polls (steady-state: first-try hit)
__device__ __forceinline__ bool spinBail(int& guard, int* af) {
    if ((++guard & 63) == 0) {
        __builtin_amdgcn_s_sleep(1);
        if (guard > (1 << 18) || aflag(af)) { sflag(af); return true; }
    }
    return false;
}

// ---------------------------------------------------------------------------
// embed: h0 = [x | tf] @ in_W + in_b
// ---------------------------------------------------------------------------
__global__ void embed_kernel(const float* __restrict__ x, const float* __restrict__ tf,
                             const float* __restrict__ inW, const float* __restrict__ inb,
                             float* __restrict__ h) {
    int tok = blockIdx.x, d = threadIdx.x;
    float xv = x[tok];
    float acc = inb[d] + xv * inW[d];
#pragma unroll
    for (int c = 0; c < 6; ++c)
        acc = fmaf(tf[tok * 6 + c], inW[(c + 1) * DD + d], acc);
    h[(size_t)tok * DD + d] = acc;
}

// ---------------------------------------------------------------------------
// Wx -> fp16 B-fragment order: Wxh[((l*64+G)*8+kc)*64 + lane][8]
// ---------------------------------------------------------------------------
__global__ void wxprep_kernel(const float* __restrict__ Wx, unsigned short* __restrict__ Wxh) {
    int l = blockIdx.x >> 6, G = blockIdx.x & 63;
    int lane = threadIdx.x, quad = lane >> 4, mm = lane & 15;
    const float* W = Wx + (size_t)l * DD * ND4;
    unsigned short* o = Wxh + (size_t)blockIdx.x * 4096;
#pragma unroll
    for (int kc = 0; kc < 8; ++kc) {
        __align__(16) unsigned short tmp[8];
#pragma unroll
        for (int i = 0; i < 8; ++i)
            tmp[i] = f16b(W[(size_t)(kc * 32 + quad * 8 + i) * ND4 + G * 16 + mm]);
        *(uint4*)(o + ((size_t)kc * 64 + lane) * 8) = *(uint4*)tmp;
    }
}

// ---------------------------------------------------------------------------
// Mega kernel: 128 WGs x 256 thr, XCD-aware role mapping (bid%8 = XCD, m09):
//   bid%8 even (=2l), k=bid>>3 in 0..15 : scan WG (layer l, group g=k)
//   bid%8 odd  (=2l+1), k<4             : helper WG (layer l, j=k)
//   else: dummy, exits.
// X exchange fast path (same-XCD L2: plain wg-store + buffer_inv sc1 + plain
// wide load) is enabled ONLY after passing BOTH runtime gates:
//   (1) HW_REG_XCC_ID vote: all 16 scan WGs of the layer on one XCD;
//   (2) mechanism self-test: readers cache a stale line, writer plain-stores
//       MAGIC, readers must observe it via the exact inv+load recipe.
// Any failure -> proven agent-scope path. GX/R stay agent (cross-XCD) but are
// prefetched one step ahead (tag-checked), issued after the X-poll.
// ---------------------------------------------------------------------------
__global__ __launch_bounds__(256, 1) void mega_kernel(
    const float* __restrict__ hemb, const float* __restrict__ Wh,
    const float* __restrict__ lng, const float* __restrict__ lnb,
    const float* __restrict__ bgp, const unsigned short* __restrict__ Wxh,
    float* __restrict__ hout,
    u64* __restrict__ Xbuf, u64* __restrict__ Rbuf, u64* __restrict__ GXbuf,
    unsigned* __restrict__ prog, int* __restrict__ abortFlag) {
    __shared__ __align__(16) char smemBlob[57344];  // 56KB
    __shared__ int fastFlag;
    const int bid = blockIdx.x;
    const int tid = threadIdx.x;
    const int xslot = bid & 7;       // presumed XCD (round-robin, m09)
    const int ksl = bid >> 3;        // slot index within that XCD, 0..15
    const int l = xslot >> 1;
    const bool isScan = ((xslot & 1) == 0);
    if (!isScan && ksl >= HLP) return;  // dummy WG

    if (isScan) {
        // ================= SCAN ROLE =================
        const int g = ksl;
        const int w = tid >> 6, lane = tid & 63;
        const int mm = lane & 15, quad = lane >> 4;
        const int sb = tid >> 4, sd = tid & 15;
        const int dglob = g * 16 + sd;
        float (*gbuf)[4][16][16] = (float (*)[4][16][16])smemBlob;

        // publish our XCC id early (overlaps with Wh fragment load)
        unsigned* xt = prog + 32 + l * 16;
        if (tid == 0) {
            unsigned xcc;
            asm volatile("s_getreg_b32 %0, hwreg(HW_REG_XCC_ID)" : "=s"(xcc));
            pstore(xt + g, xcc + 1u);
        }

        H8 bfr[8];
        {
            const float* WhL = Wh + (size_t)l * DD * ND4;
            const int col = w * 256 + g * 16 + mm;
#pragma unroll
            for (int kc = 0; kc < 8; ++kc)
#pragma unroll
                for (int p = 0; p < 4; ++p) {
                    float f0 = WhL[(size_t)(32 * kc + 8 * quad + 2 * p) * ND4 + col];
                    float f1 = WhL[(size_t)(32 * kc + 8 * quad + 2 * p + 1) * ND4 + col];
                    bfr[kc].u[p] = (unsigned)f16b(f0) | ((unsigned)f16b(f1) << 16);
                }
        }

        // ---- gate 1: placement vote; gate 2: mechanism self-test ----
        if (tid == 0) {
            bool plOK = true;
            {
                unsigned ref = 0;
                for (int i = 0; i < 16; ++i) {
                    unsigned v = 0; int gu = 0;
                    for (;;) { v = pload(xt + i); if (v) break; if (++gu > (1 << 18)) break; }
                    if (v == 0) { plOK = false; break; }
                    if (i == 0) ref = v; else plOK &= (v == ref);
                }
            }
            unsigned* ready  = prog + 96 + l * 16;
            unsigned* result = prog + 160 + l * 16;
            u64* tw = (u64*)(prog + 24) + l;
            const u64 MAGIC = 0x5A5A5A5ADEADBEEFULL;
            if (!plOK) {
                pstore(result + g, 1u);   // placement bad -> mark fail
            } else if (g == 0) {
                // writer: wait for readers to have cached the stale line
                int gu = 0; bool all;
                do {
                    all = true;
                    for (int i = 1; i < 16; ++i) all &= (pload(ready + i) != 0);
                } while (!all && ++gu < (1 << 20));
                wgstore(tw, MAGIC);       // the exact fast-path store flavor
                pstore(result + 0, 2u);   // "store done" marker
            } else {
                // reader: warm a STALE copy via plain loads (worst case for L1)
                u64 acc = 0;
                for (int i = 0; i < 64; ++i) acc |= *(volatile const u64*)tw;
                pstore(ready + g, 1u);
                int ok = (acc == MAGIC) ? 1 : 0, post = 0, gu = 0;
                while (!ok) {
                    u64 v;
                    asm volatile("buffer_inv sc1\n\t"
                                 "global_load_dwordx2 %0, %1, off\n\t"
                                 "s_waitcnt vmcnt(0)"
                                 : "=v"(v) : "v"(tw) : "memory");
                    if (v == MAGIC) { ok = 1; break; }
                    if (pload(result + 0) == 2u && ++post > 512) break;  // store done, never seen
                    if (++gu > (1 << 20)) break;
                }
                pstore(result + g, ok ? 2u : 1u);
            }
            // consensus over all 16 results
            bool allok = true; int gu2 = 0;
            for (int i = 0; i < 16; ++i) {
                unsigned v;
                for (;;) {
                    v = pload(result + i);
                    if (v) break;
                    if ((++gu2 & 1023) == 0) __builtin_amdgcn_s_sleep(1);
                    if (gu2 > (1 << 22)) break;
                }
                allok &= (v == 2u);
            }
            fastFlag = allok ? 1 : 0;
        }

        float c_ = 0.f, n_ = 0.f, m_ = 0.f;

        u64* Xl = Xbuf + (size_t)l * 4096;
        const u64* Rprev = Rbuf + (size_t)(l > 0 ? l - 1 : 0) * PRD * 4096;
        u64* Rcur = Rbuf + (size_t)(l < 3 ? l : 0) * PRD * 4096;
        const u64* GXl = GXbuf + (size_t)l * PGD * 16384;

        const int pquad = (dglob >> 3) & 3;
        const int ppair = (sd >> 1) & 3;
        const size_t pubIdx = (size_t)(g >> 1) * 256 + (size_t)pquad * 64 + (size_t)sb * 4 + ppair;
        const bool doPub = (sd & 1) == 0;
        const size_t rdBase = (size_t)quad * 64 + (size_t)mm * 4;
        const size_t gxIdx = (size_t)sb * 1024 + dglob;
        const size_t rIdx = (size_t)sb * 256 + dglob;
        const float* hemb0 = hemb + (size_t)sb * SS * DD + dglob;
        float* hrow = hout + (size_t)sb * SS * DD + dglob;

        // prefetch acquire-operands for t=0 (agent scope: always coherent)
        u64 pf0, pf1, pf2, pf3, pfr = 0;
        float pfh = 0.f;
        {
            const u64* Gp = GXl + gxIdx;
            pf0 = aload(Gp); pf1 = aload(Gp + 256);
            pf2 = aload(Gp + 512); pf3 = aload(Gp + 768);
            if (l > 0) pfr = aload(Rprev + rIdx);
            else pfh = hemb0[0];
        }
        __syncthreads();
        const bool fastX = (fastFlag != 0);

        // issue agent prefetch of gx/r for step t1 (called after X-poll)
        auto issuePF = [&](int t1) {
            const u64* Gp1 = GXl + (size_t)(t1 & (PGD - 1)) * 16384 + gxIdx;
            pf0 = aload(Gp1); pf1 = aload(Gp1 + 256);
            pf2 = aload(Gp1 + 512); pf3 = aload(Gp1 + 768);
            if (l > 0) pfr = aload(Rprev + (size_t)(t1 & (PRD - 1)) * 4096 + rIdx);
            else pfh = hemb0[(size_t)t1 * DD];
        };

        for (int t = 0; t < SS; ++t) {
            const unsigned tagT = (unsigned)(t + 1);
            // ---- acquire gx (+ hin residual for l>0), prefetched last step ----
            float gxi, gxf, gxz, gxoo, hin;
            {
                u64 a0 = pf0, a1 = pf1, a2 = pf2, a3 = pf3, ar = pfr;
                bool ok = ((unsigned)(a0 >> 32) == tagT) & ((unsigned)(a1 >> 32) == tagT) &
                          ((unsigned)(a2 >> 32) == tagT) & ((unsigned)(a3 >> 32) == tagT) &
                          ((l == 0) | ((unsigned)(ar >> 32) == tagT));
                if (!ok) {  // pipeline hiccup: poll fresh via agent loads
                    const u64* Gp = GXl + (size_t)(t & (PGD - 1)) * 16384 + gxIdx;
                    const u64* Rp = Rprev + (size_t)(t & (PRD - 1)) * 4096 + rIdx;
                    int guard = 0;
                    for (;;) {
                        a0 = aload(Gp); a1 = aload(Gp + 256);
                        a2 = aload(Gp + 512); a3 = aload(Gp + 768);
                        if (l > 0) ar = aload(Rp);
                        ok = ((unsigned)(a0 >> 32) == tagT) & ((unsigned)(a1 >> 32) == tagT) &
                             ((unsigned)(a2 >> 32) == tagT) & ((unsigned)(a3 >> 32) == tagT) &
                             ((l == 0) | ((unsigned)(ar >> 32) == tagT));
                        if (ok) break;
                        if (spinBail(guard, abortFlag)) break;
                    }
                }
                gxi = __uint_as_float((unsigned)a0);
                gxf = __uint_as_float((unsigned)a1);
                gxz = __uint_as_float((unsigned)a2);
                gxoo = __uint_as_float((unsigned)a3);
                hin = (l > 0) ? __uint_as_float((unsigned)ar) : pfh;
            }
            // ---- Wh matmul on h_s(t-1) via X exchange ----
            f32x4 acc0 = {0.f, 0.f, 0.f, 0.f}, acc1 = {0.f, 0.f, 0.f, 0.f};
            if (t > 0) {
                const unsigned tag = (unsigned)t;
                const u64* Xp = Xl + (size_t)(t & 1) * 2048 + rdBase;
                H8 afr[8];
                if (fastX) {
                    // validated: buffer_inv sc1 (drop L1 + clean L2 lines) then
                    // plain 16B loads served by the shared XCD L2
                    U4 q[16];
                    const u64* b0 = Xp;
                    const u64* b1 = Xp + 512;
                    const u64* b2 = Xp + 1024;
                    const u64* b3 = Xp + 1536;
                    int guard = 0;
                    for (;;) {
                        asm volatile(
                            "buffer_inv sc1\n\t"
                            "global_load_dwordx4 %0,  %16, off\n\t"
                            "global_load_dwordx4 %1,  %16, off offset:16\n\t"
                            "global_load_dwordx4 %2,  %16, off offset:2048\n\t"
                            "global_load_dwordx4 %3,  %16, off offset:2064\n\t"
                            "global_load_dwordx4 %4,  %17, off\n\t"
                            "global_load_dwordx4 %5,  %17, off offset:16\n\t"
                            "global_load_dwordx4 %6,  %17, off offset:2048\n\t"
                            "global_load_dwordx4 %7,  %17, off offset:2064\n\t"
                            "global_load_dwordx4 %8,  %18, off\n\t"
                            "global_load_dwordx4 %9,  %18, off offset:16\n\t"
                            "global_load_dwordx4 %10, %18, off offset:2048\n\t"
                            "global_load_dwordx4 %11, %18, off offset:2064\n\t"
                            "global_load_dwordx4 %12, %19, off\n\t"
                            "global_load_dwordx4 %13, %19, off offset:16\n\t"
                            "global_load_dwordx4 %14, %19, off offset:2048\n\t"
                            "global_load_dwordx4 %15, %19, off offset:2064\n\t"
                            "s_waitcnt vmcnt(0)"
                            : "=&v"(q[0].v), "=&v"(q[1].v), "=&v"(q[2].v), "=&v"(q[3].v),
                              "=&v"(q[4].v), "=&v"(q[5].v), "=&v"(q[6].v), "=&v"(q[7].v),
                              "=&v"(q[8].v), "=&v"(q[9].v), "=&v"(q[10].v), "=&v"(q[11].v),
                              "=&v"(q[12].v), "=&v"(q[13].v), "=&v"(q[14].v), "=&v"(q[15].v)
                            : "v"(b0), "v"(b1), "v"(b2), "v"(b3)
                            : "memory");
                        bool ok = true;
#pragma unroll
                        for (int i = 0; i < 16; ++i)
                            ok &= (q[i].u[1] == tag) & (q[i].u[3] == tag);
                        if (ok) break;
                        if ((++guard & 255) == 0) {
                            if (guard > (1 << 18) || aflag(abortFlag)) { sflag(abortFlag); break; }
                        }
                    }
#pragma unroll
                    for (int kc = 0; kc < 8; ++kc) {
                        afr[kc].u[0] = q[kc * 2].u[0];
                        afr[kc].u[1] = q[kc * 2].u[2];
                        afr[kc].u[2] = q[kc * 2 + 1].u[0];
                        afr[kc].u[3] = q[kc * 2 + 1].u[2];
                    }
                } else {
                    // fallback: proven agent-scope path
                    u64 v[32];
                    int guard = 0;
                    for (;;) {
#pragma unroll
                        for (int kc = 0; kc < 8; ++kc)
#pragma unroll
                            for (int p = 0; p < 4; ++p)
                                v[kc * 4 + p] = aload(Xp + (size_t)kc * 256 + p);
                        bool ok = true;
#pragma unroll
                        for (int i = 0; i < 32; ++i) ok &= ((unsigned)(v[i] >> 32) == tag);
                        if (ok) break;
                        if ((++guard & 255) == 0) {
                            if (guard > (1 << 18) || aflag(abortFlag)) { sflag(abortFlag); break; }
                        }
                    }
#pragma unroll
                    for (int kc = 0; kc < 8; ++kc)
#pragma unroll
                        for (int p = 0; p < 4; ++p) afr[kc].u[p] = (unsigned)v[kc * 4 + p];
                }
                // prefetch t+1 now (post-inv: loads read fresh L2/LLC),
                // flies under the MFMA + gates + stores below
                issuePF(t + 1 < SS ? t + 1 : t);
                acc0 = __builtin_amdgcn_mfma_f32_16x16x32_f16(afr[0].v, bfr[0].v, acc0, 0, 0, 0);
                acc1 = __builtin_amdgcn_mfma_f32_16x16x32_f16(afr[1].v, bfr[1].v, acc1, 0, 0, 0);
                acc0 = __builtin_amdgcn_mfma_f32_16x16x32_f16(afr[2].v, bfr[2].v, acc0, 0, 0, 0);
                acc1 = __builtin_amdgcn_mfma_f32_16x16x32_f16(afr[3].v, bfr[3].v, acc1, 0, 0, 0);
                acc0 = __builtin_amdgcn_mfma_f32_16x16x32_f16(afr[4].v, bfr[4].v, acc0, 0, 0, 0);
                acc1 = __builtin_amdgcn_mfma_f32_16x16x32_f16(afr[5].v, bfr[5].v, acc1, 0, 0, 0);
                acc0 = __builtin_amdgcn_mfma_f32_16x16x32_f16(afr[6].v, bfr[6].v, acc0, 0, 0, 0);
                acc1 = __builtin_amdgcn_mfma_f32_16x16x32_f16(afr[7].v, bfr[7].v, acc1, 0, 0, 0);
            } else {
                issuePF(1);
            }
            f32x4 acc = acc0 + acc1;
            const int par = t & 1;
#pragma unroll
            for (int r = 0; r < 4; ++r) gbuf[par][w][quad * 4 + r][mm] = acc[r];
            __syncthreads();
            // ---- gates ----
            float gi = gbuf[par][0][sb][sd] + gxi;
            float gf = gbuf[par][1][sb][sd] + gxf;
            float gz = gbuf[par][2][sb][sd] + gxz;
            float go = gbuf[par][3][sb][sd] + gxoo;
            float mn = fmaxf(gf + m_, gi);
            float ip = __expf(gi - mn);
            float fp = __expf(gf + m_ - mn);
            float e2z = __expf(2.f * gz);
            float th = 1.f - 2.f * __builtin_amdgcn_rcpf(e2z + 1.f);
            c_ = fp * c_ + ip * th;
            n_ = fp * n_ + ip;
            m_ = mn;
            float sg = __builtin_amdgcn_rcpf(1.f + __expf(-go));
            float hval = sg * c_ * __builtin_amdgcn_rcpf(fmaxf(fabsf(n_), 1.f));
            float rnew = hin + hval;
            // ---- residual out ----
            if (l == 3) {
                hrow[(size_t)t * DD] = rnew;
            } else {
                if (t >= PRD) {  // slot-reuse gate: downstream must have passed t-PRD
                    unsigned needT = (unsigned)(t - PRD);
                    const unsigned* ps = prog + (l + 1);
                    const unsigned* pg = prog + 4 + (l + 1) * 4 + (int)(needT & (HLP - 1));
                    int guard = 0;
                    while (!((pload(ps) >= needT + 2) && (pload(pg) >= needT + 1))) {
                        if (spinBail(guard, abortFlag)) break;
                    }
                }
                astore(Rcur + (size_t)(t & (PRD - 1)) * 4096 + rIdx,
                       ((u64)tagT << 32) | (u64)__float_as_uint(rnew));
            }
            // ---- publish h_s(t) for step t+1 ----
            float hodd = __shfl_down(hval, 1);
            if (doPub) {
                unsigned payload = (unsigned)f16b(hval) | ((unsigned)f16b(hodd) << 16);
                u64 pv = ((u64)tagT << 32) | (u64)payload;
                u64* dst = Xl + (size_t)((t + 1) & 1) * 2048 + pubIdx;
                if (fastX) wgstore(dst, pv);   // write-through into XCD-local L2
                else astore(dst, pv);
            }
            __syncthreads();
            if (g == 0 && tid == 0) pstore(prog + l, (unsigned)(t + 1));
        }
    } else {
        // ================= HELPER ROLE: streaming gx GEMM =================
        const int j = ksl;
        const int w = tid >> 6, lane = tid & 63;
        const int mm = lane & 15, quad = lane >> 4;
        const int hb_ = tid >> 4, hd0 = (tid & 15) * 16;
        unsigned short (*hA)[264] = (unsigned short (*)[264])smemBlob;

        const u64* Rin = Rbuf + (size_t)(l > 0 ? l - 1 : 0) * PRD * 4096;
        u64* GXl = GXbuf + (size_t)l * PGD * 16384;
        const unsigned short* WxL = Wxh + (size_t)l * 262144;
        const float* lngL = lng + l * DD;
        const float* lnbL = lnb + l * DD;
        const float* bgL = bgp + (size_t)l * ND4;
        unsigned* myProg = prog + 4 + l * 4 + j;
        const unsigned* scanProg = prog + l;

        for (int t = j; t < SS; t += HLP) {
            const unsigned tagT = (unsigned)(t + 1);
            // ---- 1. acquire r[l-1][t] (or embed for l==0) ----
            float rv[16];
            if (l == 0) {
                const float4* p = (const float4*)(hemb + ((size_t)hb_ * SS + t) * DD + hd0);
#pragma unroll
                for (int q4 = 0; q4 < 4; ++q4) {
                    float4 f = p[q4];
                    rv[q4 * 4 + 0] = f.x; rv[q4 * 4 + 1] = f.y;
                    rv[q4 * 4 + 2] = f.z; rv[q4 * 4 + 3] = f.w;
                }
            } else {
                const u64* Rp = Rin + (size_t)(t & (PRD - 1)) * 4096 + (size_t)tid * 16;
                int guard = 0;
                for (;;) {
                    u64 vv[16];
#pragma unroll
                    for (int i = 0; i < 16; ++i) vv[i] = aload(Rp + i);
                    bool ok = true;
#pragma unroll
                    for (int i = 0; i < 16; ++i) ok &= ((unsigned)(vv[i] >> 32) == tagT);
                    if (ok) {
#pragma unroll
                        for (int i = 0; i < 16; ++i) rv[i] = __uint_as_float((unsigned)vv[i]);
                        break;
                    }
                    if (spinBail(guard, abortFlag)) {
#pragma unroll
                        for (int i = 0; i < 16; ++i) rv[i] = 0.f;
                        break;
                    }
                }
            }
            // ---- 2. LN stats (16 threads per batch, shfl-xor reduce) ----
            float s = 0.f, ssq = 0.f;
#pragma unroll
            for (int i = 0; i < 16; ++i) { s += rv[i]; ssq += rv[i] * rv[i]; }
#pragma unroll
            for (int msk = 1; msk < 16; msk <<= 1) {
                s += __shfl_xor(s, msk);
                ssq += __shfl_xor(ssq, msk);
            }
            float muv = s * (1.f / 256.f);
            float rsv = rsqrtf(fmaxf(ssq * (1.f / 256.f) - muv * muv, 0.f) + 1e-5f);
            // ---- 3. LN -> fp16 -> LDS (A-matrix rows = batches) ----
            {
                __align__(16) unsigned short ov[16];
#pragma unroll
                for (int i = 0; i < 16; ++i)
                    ov[i] = f16b((rv[i] - muv) * rsv * lngL[hd0 + i] + lnbL[hd0 + i]);
                *(uint4*)&hA[hb_][hd0] = *(uint4*)&ov[0];
                *(uint4*)&hA[hb_][hd0 + 8] = *(uint4*)&ov[8];
            }
            __syncthreads();
            // ---- 4. A-frags from LDS ----
            H8 A[8];
#pragma unroll
            for (int kc = 0; kc < 8; ++kc)
                A[kc].q = *(const uint4*)&hA[mm][kc * 32 + quad * 8];
            // ---- 5. 16 tiles x 8 chunks MFMA, B streamed from L2 ----
            f32x4 acc[16];
            const unsigned short* WxW = WxL + (size_t)w * 16 * 4096;
#pragma unroll
            for (int n = 0; n < 16; ++n) {
                const unsigned short* bp = WxW + (size_t)n * 4096 + (size_t)lane * 8;
                f32x4 a = {0.f, 0.f, 0.f, 0.f};
#pragma unroll
                for (int kc = 0; kc < 8; ++kc) {
                    H8 B;
                    B.q = *(const uint4*)(bp + (size_t)kc * 512);
                    a = __builtin_amdgcn_mfma_f32_16x16x32_f16(A[kc].v, B.v, a, 0, 0, 0);
                }
                acc[n] = a;
            }
            // ---- 6. slot-reuse gate, then write GX ----
            if (t >= PGD) {
                unsigned need = (unsigned)(t - PGD) + 2;
                int guard = 0;
                while (pload(scanProg) < need) {
                    if (spinBail(guard, abortFlag)) break;
                }
            }
            u64* Gq = GXl + (size_t)(t & (PGD - 1)) * 16384;
#pragma unroll
            for (int n = 0; n < 16; ++n) {
                int c = (w * 16 + n) * 16 + mm;
                float bgv = bgL[c];
                f32x4 a = acc[n];
#pragma unroll
                for (int r = 0; r < 4; ++r)
                    astore(Gq + (size_t)(quad * 4 + r) * 1024 + c,
                           ((u64)tagT << 32) | (u64)__float_as_uint(a[r] + bgv));
            }
            __syncthreads();  // covers hA WAR for next token + read-phase completion
            if (tid == 0) pstore(myProg, (unsigned)(t + 1));
        }
    }
}

// ---------------------------------------------------------------------------
// final: out[b] = r3[b][S-1][:] . fc_W + fc_b
// ---------------------------------------------------------------------------
__global__ void final_kernel(const float* __restrict__ h, const float* __restrict__ fcW,
                             const float* __restrict__ fcb, float* __restrict__ out) {
    int b = blockIdx.x, lane = threadIdx.x;
    const float4 hv = *(const float4*)(h + ((size_t)b * SS + (SS - 1)) * DD + lane * 4);
    const float4 wv = *(const float4*)(fcW + lane * 4);
    float s = hv.x * wv.x + hv.y * wv.y + hv.z * wv.z + hv.w * wv.w;
#pragma unroll
    for (int off = 32; off; off >>= 1) s += __shfl_down(s, off);
    if (lane == 0) out[b] = s + fcb[0];
}

// ---------------------------------------------------------------------------
extern "C" void kernel_launch(void* const* d_in, const int* in_sizes, int n_in,
                              void* d_out, int out_size, void* d_ws, size_t ws_size,
                              hipStream_t stream) {
    const float* x   = (const float*)d_in[0];
    const float* tf  = (const float*)d_in[1];
    const float* inW = (const float*)d_in[2];
    const float* inb = (const float*)d_in[3];
    const float* lng = (const float*)d_in[4];
    const float* lnb = (const float*)d_in[5];
    const float* Wx  = (const float*)d_in[6];
    const float* Wh  = (const float*)d_in[7];
    const float* bg  = (const float*)d_in[8];
    const float* fcW = (const float*)d_in[9];
    const float* fcb = (const float*)d_in[10];
    float* out = (float*)d_out;

    const size_t nTok = (size_t)BB * SS;
    float* hemb = (float*)d_ws;                                   // 8,388,608 f
    float* hout = hemb + nTok * DD;                               // 8,388,608 f
    unsigned short* Wxh = (unsigned short*)(hout + nTok * DD);    // 1,048,576 us
    u64* Xbuf = (u64*)(Wxh + 1048576);                            // 4*2*2048
    u64* Rbuf = Xbuf + 4 * 2 * 2048;                              // 3*16*4096
    u64* GXbuf = Rbuf + 3 * PRD * 4096;                           // 4*8*16384
    // prog area: [0..19]=prog, [20]=abort, [24..31]=test words (u64 x4),
    // [32..95]=xccTab, [96..159]=ready, [160..223]=result
    unsigned* prog = (unsigned*)(GXbuf + 4 * PGD * 16384);
    int* abortFlag = (int*)(prog + 20);

    const size_t needed = (size_t)((char*)(prog + 256) - (char*)d_ws);
    if (ws_size < needed) return;  // fail visibly instead of corrupting

    hipMemsetAsync(prog, 0, 256 * sizeof(unsigned), stream);
    // X/R/GX need no init: 0xAA poison never matches a tag in [1,2048]

    embed_kernel<<<nTok, DD, 0, stream>>>(x, tf, inW, inb, hemb);
    wxprep_kernel<<<4 * 64, 64, 0, stream>>>(Wx, Wxh);
    mega_kernel<<<128, 256, 0, stream>>>(hemb, Wh, lng, lnb, bg, Wxh, hout,
                                         Xbuf, Rbuf, GXbuf, prog, abortFlag);
    final_kernel<<<BB, 64, 0, stream>>>(hout, fcW, fcb, out);
    (void)in_sizes; (void)n_in; (void)out_size;
}

// Round 3
// 7024.740 us; speedup vs baseline: 1.7847x; 1.7847x over previous
//
#include <hip/hip_runtime.h>

// Problem constants
#define BB 16
#define SS 2048
#define DD 256
#define ND4 1024   // 4*D
#define PRD 16     // R-buffer slot depth (residual stream)
#define PGD 8      // GX-buffer slot depth (gate pre-activations)
#define HLP 4      // helper WGs per layer

typedef __attribute__((ext_vector_type(8))) _Float16 half8;
typedef __attribute__((ext_vector_type(4))) float f32x4;
typedef __attribute__((ext_vector_type(4))) unsigned int u32x4;
typedef unsigned long long u64;
union H8 { half8 v; unsigned int u[4]; uint4 q; };
union U4 { u32x4 v; unsigned int u[4]; };

__device__ __forceinline__ u64 aload(const u64* p) {
    return __hip_atomic_load(p, __ATOMIC_RELAXED, __HIP_MEMORY_SCOPE_AGENT);
}
__device__ __forceinline__ void astore(u64* p, u64 v) {
    __hip_atomic_store(p, v, __ATOMIC_RELAXED, __HIP_MEMORY_SCOPE_AGENT);
}
// fast path: plain store (write-through L1 -> lands in XCD-local L2)
__device__ __forceinline__ void wgstore(u64* p, u64 v) {
    __hip_atomic_store(p, v, __ATOMIC_RELAXED, __HIP_MEMORY_SCOPE_WORKGROUP);
}
__device__ __forceinline__ unsigned pload(const unsigned* p) {
    return __hip_atomic_load(p, __ATOMIC_RELAXED, __HIP_MEMORY_SCOPE_AGENT);
}
__device__ __forceinline__ void pstore(unsigned* p, unsigned v) {
    __hip_atomic_store(p, v, __ATOMIC_RELAXED, __HIP_MEMORY_SCOPE_AGENT);
}
__device__ __forceinline__ int aflag(int* p) {
    return __hip_atomic_load(p, __ATOMIC_RELAXED, __HIP_MEMORY_SCOPE_AGENT);
}
__device__ __forceinline__ void sflag(int* p) {
    __hip_atomic_store(p, 1, __ATOMIC_RELAXED, __HIP_MEMORY_SCOPE_AGENT);
}
__device__ __forceinline__ unsigned short f16b(float x) {
    union { _Float16 h; unsigned short u; } c; c.h = (_Float16)x; return c.u;
}
// spin guard with backoff for cross-layer polls (steady-state: first-try hit)
__device__ __forceinline__ bool spinBail(int& guard, int* af) {
    if ((++guard & 63) == 0) {
        __builtin_amdgcn_s_sleep(1);
        if (guard > (1 << 18) || aflag(af)) { sflag(af); return true; }
    }
    return false;
}

// ---------------------------------------------------------------------------
// embed: h0 = [x | tf] @ in_W + in_b
// ---------------------------------------------------------------------------
__global__ void embed_kernel(const float* __restrict__ x, const float* __restrict__ tf,
                             const float* __restrict__ inW, const float* __restrict__ inb,
                             float* __restrict__ h) {
    int tok = blockIdx.x, d = threadIdx.x;
    float xv = x[tok];
    float acc = inb[d] + xv * inW[d];
#pragma unroll
    for (int c = 0; c < 6; ++c)
        acc = fmaf(tf[tok * 6 + c], inW[(c + 1) * DD + d], acc);
    h[(size_t)tok * DD + d] = acc;
}

// ---------------------------------------------------------------------------
// Wx -> fp16 B-fragment order: Wxh[((l*64+G)*8+kc)*64 + lane][8]
// ---------------------------------------------------------------------------
__global__ void wxprep_kernel(const float* __restrict__ Wx, unsigned short* __restrict__ Wxh) {
    int l = blockIdx.x >> 6, G = blockIdx.x & 63;
    int lane = threadIdx.x, quad = lane >> 4, mm = lane & 15;
    const float* W = Wx + (size_t)l * DD * ND4;
    unsigned short* o = Wxh + (size_t)blockIdx.x * 4096;
#pragma unroll
    for (int kc = 0; kc < 8; ++kc) {
        __align__(16) unsigned short tmp[8];
#pragma unroll
        for (int i = 0; i < 8; ++i)
            tmp[i] = f16b(W[(size_t)(kc * 32 + quad * 8 + i) * ND4 + G * 16 + mm]);
        *(uint4*)(o + ((size_t)kc * 64 + lane) * 8) = *(uint4*)tmp;
    }
}

// ---------------------------------------------------------------------------
// Mega kernel: 128 WGs x 256 thr, XCD-aware role mapping (bid%8 = XCD, m09):
//   bid%8 even (=2l), k=bid>>3 in 0..15 : scan WG (layer l, group g=k)
//   bid%8 odd  (=2l+1), k<4             : helper WG (layer l, j=k)
//   else: dummy, exits.
// X exchange fast path: plain wg-store (write-through L1 -> shared XCD L2),
// reader does `buffer_inv sc0` (drop OWN CU L1 only; L2 untouched -- the sc1
// flavor invalidates the whole XCD L2 and caused the round-2 2-7x regression)
// then plain wide loads that L2-hit peer data. Enabled ONLY after:
//   (1) HW_REG_XCC_ID vote: all 16 scan WGs of the layer on one XCD;
//   (2) mechanism self-test with the EXACT store/inv/load recipe.
// Any failure -> proven agent-scope path. GX/R stay agent (cross-XCD) but are
// prefetched one step ahead (tag-checked), issued after the X-poll.
// ---------------------------------------------------------------------------
__global__ __launch_bounds__(256, 1) void mega_kernel(
    const float* __restrict__ hemb, const float* __restrict__ Wh,
    const float* __restrict__ lng, const float* __restrict__ lnb,
    const float* __restrict__ bgp, const unsigned short* __restrict__ Wxh,
    float* __restrict__ hout,
    u64* __restrict__ Xbuf, u64* __restrict__ Rbuf, u64* __restrict__ GXbuf,
    unsigned* __restrict__ prog, int* __restrict__ abortFlag) {
    __shared__ __align__(16) char smemBlob[57344];  // 56KB
    __shared__ int fastFlag;
    const int bid = blockIdx.x;
    const int tid = threadIdx.x;
    const int xslot = bid & 7;       // presumed XCD (round-robin, m09)
    const int ksl = bid >> 3;        // slot index within that XCD, 0..15
    const int l = xslot >> 1;
    const bool isScan = ((xslot & 1) == 0);
    if (!isScan && ksl >= HLP) return;  // dummy WG

    if (isScan) {
        // ================= SCAN ROLE =================
        const int g = ksl;
        const int w = tid >> 6, lane = tid & 63;
        const int mm = lane & 15, quad = lane >> 4;
        const int sb = tid >> 4, sd = tid & 15;
        const int dglob = g * 16 + sd;
        float (*gbuf)[4][16][16] = (float (*)[4][16][16])smemBlob;

        // publish our XCC id early (overlaps with Wh fragment load)
        unsigned* xt = prog + 32 + l * 16;
        if (tid == 0) {
            unsigned xcc;
            asm volatile("s_getreg_b32 %0, hwreg(HW_REG_XCC_ID)" : "=s"(xcc));
            pstore(xt + g, xcc + 1u);
        }

        H8 bfr[8];
        {
            const float* WhL = Wh + (size_t)l * DD * ND4;
            const int col = w * 256 + g * 16 + mm;
#pragma unroll
            for (int kc = 0; kc < 8; ++kc)
#pragma unroll
                for (int p = 0; p < 4; ++p) {
                    float f0 = WhL[(size_t)(32 * kc + 8 * quad + 2 * p) * ND4 + col];
                    float f1 = WhL[(size_t)(32 * kc + 8 * quad + 2 * p + 1) * ND4 + col];
                    bfr[kc].u[p] = (unsigned)f16b(f0) | ((unsigned)f16b(f1) << 16);
                }
        }

        // ---- gate 1: placement vote; gate 2: mechanism self-test ----
        if (tid == 0) {
            bool plOK = true;
            {
                unsigned ref = 0;
                for (int i = 0; i < 16; ++i) {
                    unsigned v = 0; int gu = 0;
                    for (;;) { v = pload(xt + i); if (v) break; if (++gu > (1 << 18)) break; }
                    if (v == 0) { plOK = false; break; }
                    if (i == 0) ref = v; else plOK &= (v == ref);
                }
            }
            unsigned* ready  = prog + 96 + l * 16;
            unsigned* result = prog + 160 + l * 16;
            u64* tw = (u64*)(prog + 24) + l;
            const u64 MAGIC = 0x5A5A5A5ADEADBEEFULL;
            if (!plOK) {
                pstore(result + g, 1u);   // placement bad -> mark fail
            } else if (g == 0) {
                // writer: wait for readers to have cached the stale line
                int gu = 0; bool all;
                do {
                    all = true;
                    for (int i = 1; i < 16; ++i) all &= (pload(ready + i) != 0);
                } while (!all && ++gu < (1 << 20));
                wgstore(tw, MAGIC);       // the exact fast-path store flavor
                pstore(result + 0, 2u);   // "store done" marker
            } else {
                // reader: warm a STALE copy via plain loads (worst case for L1)
                u64 acc = 0;
                for (int i = 0; i < 64; ++i) acc |= *(volatile const u64*)tw;
                pstore(ready + g, 1u);
                int ok = (acc == MAGIC) ? 1 : 0, post = 0, gu = 0;
                while (!ok) {
                    u64 v;
                    asm volatile("buffer_inv sc0\n\t"
                                 "global_load_dwordx2 %0, %1, off\n\t"
                                 "s_waitcnt vmcnt(0)"
                                 : "=v"(v) : "v"(tw) : "memory");
                    if (v == MAGIC) { ok = 1; break; }
                    if (pload(result + 0) == 2u && ++post > 512) break;  // store done, never seen
                    if (++gu > (1 << 20)) break;
                }
                pstore(result + g, ok ? 2u : 1u);
            }
            // consensus over all 16 results
            bool allok = true; int gu2 = 0;
            for (int i = 0; i < 16; ++i) {
                unsigned v;
                for (;;) {
                    v = pload(result + i);
                    if (v) break;
                    if ((++gu2 & 1023) == 0) __builtin_amdgcn_s_sleep(1);
                    if (gu2 > (1 << 22)) break;
                }
                allok &= (v == 2u);
            }
            fastFlag = allok ? 1 : 0;
        }

        float c_ = 0.f, n_ = 0.f, m_ = 0.f;

        u64* Xl = Xbuf + (size_t)l * 4096;
        const u64* Rprev = Rbuf + (size_t)(l > 0 ? l - 1 : 0) * PRD * 4096;
        u64* Rcur = Rbuf + (size_t)(l < 3 ? l : 0) * PRD * 4096;
        const u64* GXl = GXbuf + (size_t)l * PGD * 16384;

        const int pquad = (dglob >> 3) & 3;
        const int ppair = (sd >> 1) & 3;
        const size_t pubIdx = (size_t)(g >> 1) * 256 + (size_t)pquad * 64 + (size_t)sb * 4 + ppair;
        const bool doPub = (sd & 1) == 0;
        const size_t rdBase = (size_t)quad * 64 + (size_t)mm * 4;
        const size_t gxIdx = (size_t)sb * 1024 + dglob;
        const size_t rIdx = (size_t)sb * 256 + dglob;
        const float* hemb0 = hemb + (size_t)sb * SS * DD + dglob;
        float* hrow = hout + (size_t)sb * SS * DD + dglob;

        // prefetch acquire-operands for t=0 (agent scope: always coherent)
        u64 pf0, pf1, pf2, pf3, pfr = 0;
        float pfh = 0.f;
        {
            const u64* Gp = GXl + gxIdx;
            pf0 = aload(Gp); pf1 = aload(Gp + 256);
            pf2 = aload(Gp + 512); pf3 = aload(Gp + 768);
            if (l > 0) pfr = aload(Rprev + rIdx);
            else pfh = hemb0[0];
        }
        __syncthreads();
        const bool fastX = (fastFlag != 0);

        // issue agent prefetch of gx/r for step t1 (called after X-poll)
        auto issuePF = [&](int t1) {
            const u64* Gp1 = GXl + (size_t)(t1 & (PGD - 1)) * 16384 + gxIdx;
            pf0 = aload(Gp1); pf1 = aload(Gp1 + 256);
            pf2 = aload(Gp1 + 512); pf3 = aload(Gp1 + 768);
            if (l > 0) pfr = aload(Rprev + (size_t)(t1 & (PRD - 1)) * 4096 + rIdx);
            else pfh = hemb0[(size_t)t1 * DD];
        };

        for (int t = 0; t < SS; ++t) {
            const unsigned tagT = (unsigned)(t + 1);
            // ---- acquire gx (+ hin residual for l>0), prefetched last step ----
            float gxi, gxf, gxz, gxoo, hin;
            {
                u64 a0 = pf0, a1 = pf1, a2 = pf2, a3 = pf3, ar = pfr;
                bool ok = ((unsigned)(a0 >> 32) == tagT) & ((unsigned)(a1 >> 32) == tagT) &
                          ((unsigned)(a2 >> 32) == tagT) & ((unsigned)(a3 >> 32) == tagT) &
                          ((l == 0) | ((unsigned)(ar >> 32) == tagT));
                if (!ok) {  // pipeline hiccup: poll fresh via agent loads
                    const u64* Gp = GXl + (size_t)(t & (PGD - 1)) * 16384 + gxIdx;
                    const u64* Rp = Rprev + (size_t)(t & (PRD - 1)) * 4096 + rIdx;
                    int guard = 0;
                    for (;;) {
                        a0 = aload(Gp); a1 = aload(Gp + 256);
                        a2 = aload(Gp + 512); a3 = aload(Gp + 768);
                        if (l > 0) ar = aload(Rp);
                        ok = ((unsigned)(a0 >> 32) == tagT) & ((unsigned)(a1 >> 32) == tagT) &
                             ((unsigned)(a2 >> 32) == tagT) & ((unsigned)(a3 >> 32) == tagT) &
                             ((l == 0) | ((unsigned)(ar >> 32) == tagT));
                        if (ok) break;
                        if (spinBail(guard, abortFlag)) break;
                    }
                }
                gxi = __uint_as_float((unsigned)a0);
                gxf = __uint_as_float((unsigned)a1);
                gxz = __uint_as_float((unsigned)a2);
                gxoo = __uint_as_float((unsigned)a3);
                hin = (l > 0) ? __uint_as_float((unsigned)ar) : pfh;
            }
            // ---- Wh matmul on h_s(t-1) via X exchange ----
            f32x4 acc0 = {0.f, 0.f, 0.f, 0.f}, acc1 = {0.f, 0.f, 0.f, 0.f};
            if (t > 0) {
                const unsigned tag = (unsigned)t;
                const u64* Xp = Xl + (size_t)(t & 1) * 2048 + rdBase;
                H8 afr[8];
                if (fastX) {
                    // validated: buffer_inv sc0 (drop own L1 only) then plain
                    // 16B loads served by the shared XCD L2
                    U4 q[16];
                    const u64* b0 = Xp;
                    const u64* b1 = Xp + 512;
                    const u64* b2 = Xp + 1024;
                    const u64* b3 = Xp + 1536;
                    int guard = 0;
                    for (;;) {
                        asm volatile(
                            "buffer_inv sc0\n\t"
                            "global_load_dwordx4 %0,  %16, off\n\t"
                            "global_load_dwordx4 %1,  %16, off offset:16\n\t"
                            "global_load_dwordx4 %2,  %16, off offset:2048\n\t"
                            "global_load_dwordx4 %3,  %16, off offset:2064\n\t"
                            "global_load_dwordx4 %4,  %17, off\n\t"
                            "global_load_dwordx4 %5,  %17, off offset:16\n\t"
                            "global_load_dwordx4 %6,  %17, off offset:2048\n\t"
                            "global_load_dwordx4 %7,  %17, off offset:2064\n\t"
                            "global_load_dwordx4 %8,  %18, off\n\t"
                            "global_load_dwordx4 %9,  %18, off offset:16\n\t"
                            "global_load_dwordx4 %10, %18, off offset:2048\n\t"
                            "global_load_dwordx4 %11, %18, off offset:2064\n\t"
                            "global_load_dwordx4 %12, %19, off\n\t"
                            "global_load_dwordx4 %13, %19, off offset:16\n\t"
                            "global_load_dwordx4 %14, %19, off offset:2048\n\t"
                            "global_load_dwordx4 %15, %19, off offset:2064\n\t"
                            "s_waitcnt vmcnt(0)"
                            : "=&v"(q[0].v), "=&v"(q[1].v), "=&v"(q[2].v), "=&v"(q[3].v),
                              "=&v"(q[4].v), "=&v"(q[5].v), "=&v"(q[6].v), "=&v"(q[7].v),
                              "=&v"(q[8].v), "=&v"(q[9].v), "=&v"(q[10].v), "=&v"(q[11].v),
                              "=&v"(q[12].v), "=&v"(q[13].v), "=&v"(q[14].v), "=&v"(q[15].v)
                            : "v"(b0), "v"(b1), "v"(b2), "v"(b3)
                            : "memory");
                        bool ok = true;
#pragma unroll
                        for (int i = 0; i < 16; ++i)
                            ok &= (q[i].u[1] == tag) & (q[i].u[3] == tag);
                        if (ok) break;
                        if ((++guard & 255) == 0) {
                            if (guard > (1 << 18) || aflag(abortFlag)) { sflag(abortFlag); break; }
                        }
                    }
#pragma unroll
                    for (int kc = 0; kc < 8; ++kc) {
                        afr[kc].u[0] = q[kc * 2].u[0];
                        afr[kc].u[1] = q[kc * 2].u[2];
                        afr[kc].u[2] = q[kc * 2 + 1].u[0];
                        afr[kc].u[3] = q[kc * 2 + 1].u[2];
                    }
                } else {
                    // fallback: proven agent-scope path
                    u64 v[32];
                    int guard = 0;
                    for (;;) {
#pragma unroll
                        for (int kc = 0; kc < 8; ++kc)
#pragma unroll
                            for (int p = 0; p < 4; ++p)
                                v[kc * 4 + p] = aload(Xp + (size_t)kc * 256 + p);
                        bool ok = true;
#pragma unroll
                        for (int i = 0; i < 32; ++i) ok &= ((unsigned)(v[i] >> 32) == tag);
                        if (ok) break;
                        if ((++guard & 255) == 0) {
                            if (guard > (1 << 18) || aflag(abortFlag)) { sflag(abortFlag); break; }
                        }
                    }
#pragma unroll
                    for (int kc = 0; kc < 8; ++kc)
#pragma unroll
                        for (int p = 0; p < 4; ++p) afr[kc].u[p] = (unsigned)v[kc * 4 + p];
                }
                // prefetch t+1 now; flies under the MFMA + gates + stores below
                issuePF(t + 1 < SS ? t + 1 : t);
                acc0 = __builtin_amdgcn_mfma_f32_16x16x32_f16(afr[0].v, bfr[0].v, acc0, 0, 0, 0);
                acc1 = __builtin_amdgcn_mfma_f32_16x16x32_f16(afr[1].v, bfr[1].v, acc1, 0, 0, 0);
                acc0 = __builtin_amdgcn_mfma_f32_16x16x32_f16(afr[2].v, bfr[2].v, acc0, 0, 0, 0);
                acc1 = __builtin_amdgcn_mfma_f32_16x16x32_f16(afr[3].v, bfr[3].v, acc1, 0, 0, 0);
                acc0 = __builtin_amdgcn_mfma_f32_16x16x32_f16(afr[4].v, bfr[4].v, acc0, 0, 0, 0);
                acc1 = __builtin_amdgcn_mfma_f32_16x16x32_f16(afr[5].v, bfr[5].v, acc1, 0, 0, 0);
                acc0 = __builtin_amdgcn_mfma_f32_16x16x32_f16(afr[6].v, bfr[6].v, acc0, 0, 0, 0);
                acc1 = __builtin_amdgcn_mfma_f32_16x16x32_f16(afr[7].v, bfr[7].v, acc1, 0, 0, 0);
            } else {
                issuePF(1);
            }
            f32x4 acc = acc0 + acc1;
            const int par = t & 1;
#pragma unroll
            for (int r = 0; r < 4; ++r) gbuf[par][w][quad * 4 + r][mm] = acc[r];
            __syncthreads();
            // ---- gates ----
            float gi = gbuf[par][0][sb][sd] + gxi;
            float gf = gbuf[par][1][sb][sd] + gxf;
            float gz = gbuf[par][2][sb][sd] + gxz;
            float go = gbuf[par][3][sb][sd] + gxoo;
            float mn = fmaxf(gf + m_, gi);
            float ip = __expf(gi - mn);
            float fp = __expf(gf + m_ - mn);
            float e2z = __expf(2.f * gz);
            float th = 1.f - 2.f * __builtin_amdgcn_rcpf(e2z + 1.f);
            c_ = fp * c_ + ip * th;
            n_ = fp * n_ + ip;
            m_ = mn;
            float sg = __builtin_amdgcn_rcpf(1.f + __expf(-go));
            float hval = sg * c_ * __builtin_amdgcn_rcpf(fmaxf(fabsf(n_), 1.f));
            float rnew = hin + hval;
            // ---- residual out ----
            if (l == 3) {
                hrow[(size_t)t * DD] = rnew;
            } else {
                if (t >= PRD) {  // slot-reuse gate: downstream must have passed t-PRD
                    unsigned needT = (unsigned)(t - PRD);
                    const unsigned* ps = prog + (l + 1);
                    const unsigned* pg = prog + 4 + (l + 1) * 4 + (int)(needT & (HLP - 1));
                    int guard = 0;
                    while (!((pload(ps) >= needT + 2) && (pload(pg) >= needT + 1))) {
                        if (spinBail(guard, abortFlag)) break;
                    }
                }
                astore(Rcur + (size_t)(t & (PRD - 1)) * 4096 + rIdx,
                       ((u64)tagT << 32) | (u64)__float_as_uint(rnew));
            }
            // ---- publish h_s(t) for step t+1 ----
            float hodd = __shfl_down(hval, 1);
            if (doPub) {
                unsigned payload = (unsigned)f16b(hval) | ((unsigned)f16b(hodd) << 16);
                u64 pv = ((u64)tagT << 32) | (u64)payload;
                u64* dst = Xl + (size_t)((t + 1) & 1) * 2048 + pubIdx;
                if (fastX) wgstore(dst, pv);   // write-through into XCD-local L2
                else astore(dst, pv);
            }
            __syncthreads();
            if (g == 0 && tid == 0) pstore(prog + l, (unsigned)(t + 1));
        }
    } else {
        // ================= HELPER ROLE: streaming gx GEMM =================
        const int j = ksl;
        const int w = tid >> 6, lane = tid & 63;
        const int mm = lane & 15, quad = lane >> 4;
        const int hb_ = tid >> 4, hd0 = (tid & 15) * 16;
        unsigned short (*hA)[264] = (unsigned short (*)[264])smemBlob;

        const u64* Rin = Rbuf + (size_t)(l > 0 ? l - 1 : 0) * PRD * 4096;
        u64* GXl = GXbuf + (size_t)l * PGD * 16384;
        const unsigned short* WxL = Wxh + (size_t)l * 262144;
        const float* lngL = lng + l * DD;
        const float* lnbL = lnb + l * DD;
        const float* bgL = bgp + (size_t)l * ND4;
        unsigned* myProg = prog + 4 + l * 4 + j;
        const unsigned* scanProg = prog + l;

        for (int t = j; t < SS; t += HLP) {
            const unsigned tagT = (unsigned)(t + 1);
            // ---- 1. acquire r[l-1][t] (or embed for l==0) ----
            float rv[16];
            if (l == 0) {
                const float4* p = (const float4*)(hemb + ((size_t)hb_ * SS + t) * DD + hd0);
#pragma unroll
                for (int q4 = 0; q4 < 4; ++q4) {
                    float4 f = p[q4];
                    rv[q4 * 4 + 0] = f.x; rv[q4 * 4 + 1] = f.y;
                    rv[q4 * 4 + 2] = f.z; rv[q4 * 4 + 3] = f.w;
                }
            } else {
                const u64* Rp = Rin + (size_t)(t & (PRD - 1)) * 4096 + (size_t)tid * 16;
                int guard = 0;
                for (;;) {
                    u64 vv[16];
#pragma unroll
                    for (int i = 0; i < 16; ++i) vv[i] = aload(Rp + i);
                    bool ok = true;
#pragma unroll
                    for (int i = 0; i < 16; ++i) ok &= ((unsigned)(vv[i] >> 32) == tagT);
                    if (ok) {
#pragma unroll
                        for (int i = 0; i < 16; ++i) rv[i] = __uint_as_float((unsigned)vv[i]);
                        break;
                    }
                    if (spinBail(guard, abortFlag)) {
#pragma unroll
                        for (int i = 0; i < 16; ++i) rv[i] = 0.f;
                        break;
                    }
                }
            }
            // ---- 2. LN stats (16 threads per batch, shfl-xor reduce) ----
            float s = 0.f, ssq = 0.f;
#pragma unroll
            for (int i = 0; i < 16; ++i) { s += rv[i]; ssq += rv[i] * rv[i]; }
#pragma unroll
            for (int msk = 1; msk < 16; msk <<= 1) {
                s += __shfl_xor(s, msk);
                ssq += __shfl_xor(ssq, msk);
            }
            float muv = s * (1.f / 256.f);
            float rsv = rsqrtf(fmaxf(ssq * (1.f / 256.f) - muv * muv, 0.f) + 1e-5f);
            // ---- 3. LN -> fp16 -> LDS (A-matrix rows = batches) ----
            {
                __align__(16) unsigned short ov[16];
#pragma unroll
                for (int i = 0; i < 16; ++i)
                    ov[i] = f16b((rv[i] - muv) * rsv * lngL[hd0 + i] + lnbL[hd0 + i]);
                *(uint4*)&hA[hb_][hd0] = *(uint4*)&ov[0];
                *(uint4*)&hA[hb_][hd0 + 8] = *(uint4*)&ov[8];
            }
            __syncthreads();
            // ---- 4. A-frags from LDS ----
            H8 A[8];
#pragma unroll
            for (int kc = 0; kc < 8; ++kc)
                A[kc].q = *(const uint4*)&hA[mm][kc * 32 + quad * 8];
            // ---- 5. 16 tiles x 8 chunks MFMA, B streamed from L2 ----
            f32x4 acc[16];
            const unsigned short* WxW = WxL + (size_t)w * 16 * 4096;
#pragma unroll
            for (int n = 0; n < 16; ++n) {
                const unsigned short* bp = WxW + (size_t)n * 4096 + (size_t)lane * 8;
                f32x4 a = {0.f, 0.f, 0.f, 0.f};
#pragma unroll
                for (int kc = 0; kc < 8; ++kc) {
                    H8 B;
                    B.q = *(const uint4*)(bp + (size_t)kc * 512);
                    a = __builtin_amdgcn_mfma_f32_16x16x32_f16(A[kc].v, B.v, a, 0, 0, 0);
                }
                acc[n] = a;
            }
            // ---- 6. slot-reuse gate, then write GX ----
            if (t >= PGD) {
                unsigned need = (unsigned)(t - PGD) + 2;
                int guard = 0;
                while (pload(scanProg) < need) {
                    if (spinBail(guard, abortFlag)) break;
                }
            }
            u64* Gq = GXl + (size_t)(t & (PGD - 1)) * 16384;
#pragma unroll
            for (int n = 0; n < 16; ++n) {
                int c = (w * 16 + n) * 16 + mm;
                float bgv = bgL[c];
                f32x4 a = acc[n];
#pragma unroll
                for (int r = 0; r < 4; ++r)
                    astore(Gq + (size_t)(quad * 4 + r) * 1024 + c,
                           ((u64)tagT << 32) | (u64)__float_as_uint(a[r] + bgv));
            }
            __syncthreads();  // covers hA WAR for next token + read-phase completion
            if (tid == 0) pstore(myProg, (unsigned)(t + 1));
        }
    }
}

// ---------------------------------------------------------------------------
// final: out[b] = r3[b][S-1][:] . fc_W + fc_b
// ---------------------------------------------------------------------------
__global__ void final_kernel(const float* __restrict__ h, const float* __restrict__ fcW,
                             const float* __restrict__ fcb, float* __restrict__ out) {
    int b = blockIdx.x, lane = threadIdx.x;
    const float4 hv = *(const float4*)(h + ((size_t)b * SS + (SS - 1)) * DD + lane * 4);
    const float4 wv = *(const float4*)(fcW + lane * 4);
    float s = hv.x * wv.x + hv.y * wv.y + hv.z * wv.z + hv.w * wv.w;
#pragma unroll
    for (int off = 32; off; off >>= 1) s += __shfl_down(s, off);
    if (lane == 0) out[b] = s + fcb[0];
}

// ---------------------------------------------------------------------------
extern "C" void kernel_launch(void* const* d_in, const int* in_sizes, int n_in,
                              void* d_out, int out_size, void* d_ws, size_t ws_size,
                              hipStream_t stream) {
    const float* x   = (const float*)d_in[0];
    const float* tf  = (const float*)d_in[1];
    const float* inW = (const float*)d_in[2];
    const float* inb = (const float*)d_in[3];
    const float* lng = (const float*)d_in[4];
    const float* lnb = (const float*)d_in[5];
    const float* Wx  = (const float*)d_in[6];
    const float* Wh  = (const float*)d_in[7];
    const float* bg  = (const float*)d_in[8];
    const float* fcW = (const float*)d_in[9];
    const float* fcb = (const float*)d_in[10];
    float* out = (float*)d_out;

    const size_t nTok = (size_t)BB * SS;
    float* hemb = (float*)d_ws;                                   // 8,388,608 f
    float* hout = hemb + nTok * DD;                               // 8,388,608 f
    unsigned short* Wxh = (unsigned short*)(hout + nTok * DD);    // 1,048,576 us
    u64* Xbuf = (u64*)(Wxh + 1048576);                            // 4*2*2048
    u64* Rbuf = Xbuf + 4 * 2 * 2048;                              // 3*16*4096
    u64* GXbuf = Rbuf + 3 * PRD * 4096;                           // 4*8*16384
    // prog area: [0..19]=prog, [20]=abort, [24..31]=test words (u64 x4),
    // [32..95]=xccTab, [96..159]=ready, [160..223]=result
    unsigned* prog = (unsigned*)(GXbuf + 4 * PGD * 16384);
    int* abortFlag = (int*)(prog + 20);

    const size_t needed = (size_t)((char*)(prog + 256) - (char*)d_ws);
    if (ws_size < needed) return;  // fail visibly instead of corrupting

    hipMemsetAsync(prog, 0, 256 * sizeof(unsigned), stream);
    // X/R/GX need no init: 0xAA poison never matches a tag in [1,2048]

    embed_kernel<<<nTok, DD, 0, stream>>>(x, tf, inW, inb, hemb);
    wxprep_kernel<<<4 * 64, 64, 0, stream>>>(Wx, Wxh);
    mega_kernel<<<128, 256, 0, stream>>>(hemb, Wh, lng, lnb, bg, Wxh, hout,
                                         Xbuf, Rbuf, GXbuf, prog, abortFlag);
    final_kernel<<<BB, 64, 0, stream>>>(hout, fcW, fcb, out);
    (void)in_sizes; (void)n_in; (void)out_size;
}

// Round 5
// 6794.531 us; speedup vs baseline: 1.8452x; 1.0339x over previous
//
#include <hip/hip_runtime.h>

// Problem constants
#define BB 16
#define SS 2048
#define DD 256
#define ND4 1024   // 4*D
#define PRD 16     // R-buffer slot depth (residual stream)
#define PGD 8      // GX-buffer slot depth (gate pre-activations)
#define HLP 4      // helper WGs per layer

typedef __attribute__((ext_vector_type(8))) _Float16 half8;
typedef __attribute__((ext_vector_type(4))) float f32x4;
typedef __attribute__((ext_vector_type(4))) unsigned int u32x4;
typedef unsigned long long u64;
union H8 { half8 v; unsigned int u[4]; uint4 q; };
union U4 { u32x4 v; unsigned int u[4]; };

__device__ __forceinline__ u64 aload(const u64* p) {
    return __hip_atomic_load(p, __ATOMIC_RELAXED, __HIP_MEMORY_SCOPE_AGENT);
}
__device__ __forceinline__ void astore(u64* p, u64 v) {
    __hip_atomic_store(p, v, __ATOMIC_RELAXED, __HIP_MEMORY_SCOPE_AGENT);
}
// fast path: plain store (write-through L1 -> lands in XCD-local L2)
__device__ __forceinline__ void wgstore(u64* p, u64 v) {
    __hip_atomic_store(p, v, __ATOMIC_RELAXED, __HIP_MEMORY_SCOPE_WORKGROUP);
}
__device__ __forceinline__ unsigned pload(const unsigned* p) {
    return __hip_atomic_load(p, __ATOMIC_RELAXED, __HIP_MEMORY_SCOPE_AGENT);
}
__device__ __forceinline__ void pstore(unsigned* p, unsigned v) {
    __hip_atomic_store(p, v, __ATOMIC_RELAXED, __HIP_MEMORY_SCOPE_AGENT);
}
__device__ __forceinline__ int aflag(int* p) {
    return __hip_atomic_load(p, __ATOMIC_RELAXED, __HIP_MEMORY_SCOPE_AGENT);
}
__device__ __forceinline__ void sflag(int* p) {
    __hip_atomic_store(p, 1, __ATOMIC_RELAXED, __HIP_MEMORY_SCOPE_AGENT);
}
__device__ __forceinline__ unsigned short f16b(float x) {
    union { _Float16 h; unsigned short u; } c; c.h = (_Float16)x; return c.u;
}
__device__ __forceinline__ unsigned umin2(unsigned a, unsigned b) { return a < b ? a : b; }
// spin guard with backoff for cross-layer polls (steady-state: first-try hit)
__device__ __forceinline__ bool spinBail(int& guard, int* af) {
    if ((++guard & 63) == 0) {
        __builtin_amdgcn_s_sleep(1);
        if (guard > (1 << 18) || aflag(af)) { sflag(af); return true; }
    }
    return false;
}

// ---------------------------------------------------------------------------
// embed: h0 = [x | tf] @ in_W + in_b
// ---------------------------------------------------------------------------
__global__ void embed_kernel(const float* __restrict__ x, const float* __restrict__ tf,
                             const float* __restrict__ inW, const float* __restrict__ inb,
                             float* __restrict__ h) {
    int tok = blockIdx.x, d = threadIdx.x;
    float xv = x[tok];
    float acc = inb[d] + xv * inW[d];
#pragma unroll
    for (int c = 0; c < 6; ++c)
        acc = fmaf(tf[tok * 6 + c], inW[(c + 1) * DD + d], acc);
    h[(size_t)tok * DD + d] = acc;
}

// ---------------------------------------------------------------------------
// Wx -> fp16 B-fragment order: Wxh[((l*64+G)*8+kc)*64 + lane][8]
// ---------------------------------------------------------------------------
__global__ void wxprep_kernel(const float* __restrict__ Wx, unsigned short* __restrict__ Wxh) {
    int l = blockIdx.x >> 6, G = blockIdx.x & 63;
    int lane = threadIdx.x, quad = lane >> 4, mm = lane & 15;
    const float* W = Wx + (size_t)l * DD * ND4;
    unsigned short* o = Wxh + (size_t)blockIdx.x * 4096;
#pragma unroll
    for (int kc = 0; kc < 8; ++kc) {
        __align__(16) unsigned short tmp[8];
#pragma unroll
        for (int i = 0; i < 8; ++i)
            tmp[i] = f16b(W[(size_t)(kc * 32 + quad * 8 + i) * ND4 + G * 16 + mm]);
        *(uint4*)(o + ((size_t)kc * 64 + lane) * 8) = *(uint4*)tmp;
    }
}

// ---------------------------------------------------------------------------
// Mega kernel: 128 WGs x 256 thr, XCD-aware role mapping (bid%8 = XCD, m09):
//   bid%8 even (=2l), k=bid>>3 in 0..15 : scan WG (layer l, group g=k)
//   bid%8 odd  (=2l+1), k<4             : helper WG (layer l, j=k)
//   else: dummy, exits.
// X exchange fast path: plain wg-store (write-through L1 -> shared XCD L2) +
// reader `buffer_inv sc0` (drop own CU L1 only) + plain wide loads (L2 hits).
// Gated by (1) XCC_ID vote and (2) a mechanism self-test; else agent path.
// R4 protocol changes (ordering only, no numerics):
//   - progress-gate caching: monotone counters, cached lower bound skips the
//     LLC poll entirely; on miss, ps + all 4 pg loaded in PARALLEL, gate on
//     min(pg) (conservative).
//   - X-publish moved directly after hval (peers unblock before R-gate/store).
//   - early progress posts: scan posts prog[l]=t+1 right after poll+prefetch
//     (slot margins +2/+3 still protect all pending reads incl. lagging
//     waves); helper posts myProg right after the sync covering R-reads.
// ---------------------------------------------------------------------------
__global__ __launch_bounds__(256, 1) void mega_kernel(
    const float* __restrict__ hemb, const float* __restrict__ Wh,
    const float* __restrict__ lng, const float* __restrict__ lnb,
    const float* __restrict__ bgp, const unsigned short* __restrict__ Wxh,
    float* __restrict__ hout,
    u64* __restrict__ Xbuf, u64* __restrict__ Rbuf, u64* __restrict__ GXbuf,
    unsigned* __restrict__ prog, int* __restrict__ abortFlag) {
    __shared__ __align__(16) char smemBlob[57344];  // 56KB
    __shared__ int fastFlag;
    const int bid = blockIdx.x;
    const int tid = threadIdx.x;
    const int xslot = bid & 7;       // presumed XCD (round-robin, m09)
    const int ksl = bid >> 3;        // slot index within that XCD, 0..15
    const int l = xslot >> 1;
    const bool isScan = ((xslot & 1) == 0);
    if (!isScan && ksl >= HLP) return;  // dummy WG

    if (isScan) {
        // ================= SCAN ROLE =================
        const int g = ksl;
        const int w = tid >> 6, lane = tid & 63;
        const int mm = lane & 15, quad = lane >> 4;
        const int sb = tid >> 4, sd = tid & 15;
        const int dglob = g * 16 + sd;
        float (*gbuf)[4][16][16] = (float (*)[4][16][16])smemBlob;

        // publish our XCC id early (overlaps with Wh fragment load)
        unsigned* xt = prog + 32 + l * 16;
        if (tid == 0) {
            unsigned xcc;
            asm volatile("s_getreg_b32 %0, hwreg(HW_REG_XCC_ID)" : "=s"(xcc));
            pstore(xt + g, xcc + 1u);
        }

        H8 bfr[8];
        {
            const float* WhL = Wh + (size_t)l * DD * ND4;
            const int col = w * 256 + g * 16 + mm;
#pragma unroll
            for (int kc = 0; kc < 8; ++kc)
#pragma unroll
                for (int p = 0; p < 4; ++p) {
                    float f0 = WhL[(size_t)(32 * kc + 8 * quad + 2 * p) * ND4 + col];
                    float f1 = WhL[(size_t)(32 * kc + 8 * quad + 2 * p + 1) * ND4 + col];
                    bfr[kc].u[p] = (unsigned)f16b(f0) | ((unsigned)f16b(f1) << 16);
                }
        }

        // ---- gate 1: placement vote; gate 2: mechanism self-test ----
        if (tid == 0) {
            bool plOK = true;
            {
                unsigned ref = 0;
                for (int i = 0; i < 16; ++i) {
                    unsigned v = 0; int gu = 0;
                    for (;;) { v = pload(xt + i); if (v) break; if (++gu > (1 << 18)) break; }
                    if (v == 0) { plOK = false; break; }
                    if (i == 0) ref = v; else plOK &= (v == ref);
                }
            }
            unsigned* ready  = prog + 96 + l * 16;
            unsigned* result = prog + 160 + l * 16;
            u64* tw = (u64*)(prog + 24) + l;
            const u64 MAGIC = 0x5A5A5A5ADEADBEEFULL;
            if (!plOK) {
                pstore(result + g, 1u);   // placement bad -> mark fail
            } else if (g == 0) {
                // writer: wait for readers to have cached the stale line
                int gu = 0; bool all;
                do {
                    all = true;
                    for (int i = 1; i < 16; ++i) all &= (pload(ready + i) != 0);
                } while (!all && ++gu < (1 << 20));
                wgstore(tw, MAGIC);       // the exact fast-path store flavor
                pstore(result + 0, 2u);   // "store done" marker
            } else {
                // reader: warm a STALE copy via plain loads (worst case for L1)
                u64 acc = 0;
                for (int i = 0; i < 64; ++i) acc |= *(volatile const u64*)tw;
                pstore(ready + g, 1u);
                int ok = (acc == MAGIC) ? 1 : 0, post = 0, gu = 0;
                while (!ok) {
                    u64 v;
                    asm volatile("buffer_inv sc0\n\t"
                                 "global_load_dwordx2 %0, %1, off\n\t"
                                 "s_waitcnt vmcnt(0)"
                                 : "=v"(v) : "v"(tw) : "memory");
                    if (v == MAGIC) { ok = 1; break; }
                    if (pload(result + 0) == 2u && ++post > 512) break;  // store done, never seen
                    if (++gu > (1 << 20)) break;
                }
                pstore(result + g, ok ? 2u : 1u);
            }
            // consensus over all 16 results
            bool allok = true; int gu2 = 0;
            for (int i = 0; i < 16; ++i) {
                unsigned v;
                for (;;) {
                    v = pload(result + i);
                    if (v) break;
                    if ((++gu2 & 1023) == 0) __builtin_amdgcn_s_sleep(1);
                    if (gu2 > (1 << 22)) break;
                }
                allok &= (v == 2u);
            }
            fastFlag = allok ? 1 : 0;
        }

        float c_ = 0.f, n_ = 0.f, m_ = 0.f;

        u64* Xl = Xbuf + (size_t)l * 4096;
        const u64* Rprev = Rbuf + (size_t)(l > 0 ? l - 1 : 0) * PRD * 4096;
        u64* Rcur = Rbuf + (size_t)(l < 3 ? l : 0) * PRD * 4096;
        const u64* GXl = GXbuf + (size_t)l * PGD * 16384;

        const int pquad = (dglob >> 3) & 3;
        const int ppair = (sd >> 1) & 3;
        const size_t pubIdx = (size_t)(g >> 1) * 256 + (size_t)pquad * 64 + (size_t)sb * 4 + ppair;
        const bool doPub = (sd & 1) == 0;
        const size_t rdBase = (size_t)quad * 64 + (size_t)mm * 4;
        const size_t gxIdx = (size_t)sb * 1024 + dglob;
        const size_t rIdx = (size_t)sb * 256 + dglob;
        const float* hemb0 = hemb + (size_t)sb * SS * DD + dglob;
        float* hrow = hout + (size_t)sb * SS * DD + dglob;

        // progress-gate caches (monotone lower bounds)
        unsigned psC = 0, minPgC = 0;
        const unsigned* psP = prog + (l + 1);
        const unsigned* pgP = prog + 4 + (l + 1) * 4;

        // prefetch acquire-operands for t=0 (agent scope: always coherent)
        u64 pf0, pf1, pf2, pf3, pfr = 0;
        float pfh = 0.f;
        {
            const u64* Gp = GXl + gxIdx;
            pf0 = aload(Gp); pf1 = aload(Gp + 256);
            pf2 = aload(Gp + 512); pf3 = aload(Gp + 768);
            if (l > 0) pfr = aload(Rprev + rIdx);
            else pfh = hemb0[0];
        }
        __syncthreads();
        const bool fastX = (fastFlag != 0);

        // issue agent prefetch of gx/r for step t1 (called after X-poll)
        auto issuePF = [&](int t1) {
            const u64* Gp1 = GXl + (size_t)(t1 & (PGD - 1)) * 16384 + gxIdx;
            pf0 = aload(Gp1); pf1 = aload(Gp1 + 256);
            pf2 = aload(Gp1 + 512); pf3 = aload(Gp1 + 768);
            if (l > 0) pfr = aload(Rprev + (size_t)(t1 & (PRD - 1)) * 4096 + rIdx);
            else pfh = hemb0[(size_t)t1 * DD];
        };

        for (int t = 0; t < SS; ++t) {
            const unsigned tagT = (unsigned)(t + 1);
            // ---- acquire gx (+ hin residual for l>0), prefetched last step ----
            float gxi, gxf, gxz, gxoo, hin;
            {
                u64 a0 = pf0, a1 = pf1, a2 = pf2, a3 = pf3, ar = pfr;
                bool ok = ((unsigned)(a0 >> 32) == tagT) & ((unsigned)(a1 >> 32) == tagT) &
                          ((unsigned)(a2 >> 32) == tagT) & ((unsigned)(a3 >> 32) == tagT) &
                          ((l == 0) | ((unsigned)(ar >> 32) == tagT));
                if (!ok) {  // pipeline hiccup: poll fresh via agent loads
                    const u64* Gp = GXl + (size_t)(t & (PGD - 1)) * 16384 + gxIdx;
                    const u64* Rp = Rprev + (size_t)(t & (PRD - 1)) * 4096 + rIdx;
                    int guard = 0;
                    for (;;) {
                        a0 = aload(Gp); a1 = aload(Gp + 256);
                        a2 = aload(Gp + 512); a3 = aload(Gp + 768);
                        if (l > 0) ar = aload(Rp);
                        ok = ((unsigned)(a0 >> 32) == tagT) & ((unsigned)(a1 >> 32) == tagT) &
                             ((unsigned)(a2 >> 32) == tagT) & ((unsigned)(a3 >> 32) == tagT) &
                             ((l == 0) | ((unsigned)(ar >> 32) == tagT));
                        if (ok) break;
                        if (spinBail(guard, abortFlag)) break;
                    }
                }
                gxi = __uint_as_float((unsigned)a0);
                gxf = __uint_as_float((unsigned)a1);
                gxz = __uint_as_float((unsigned)a2);
                gxoo = __uint_as_float((unsigned)a3);
                hin = (l > 0) ? __uint_as_float((unsigned)ar) : pfh;
            }
            // ---- Wh matmul on h_s(t-1) via X exchange ----
            f32x4 acc0 = {0.f, 0.f, 0.f, 0.f}, acc1 = {0.f, 0.f, 0.f, 0.f};
            if (t > 0) {
                const unsigned tag = (unsigned)t;
                const u64* Xp = Xl + (size_t)(t & 1) * 2048 + rdBase;
                H8 afr[8];
                if (fastX) {
                    // validated: buffer_inv sc0 (drop own L1 only) then plain
                    // 16B loads served by the shared XCD L2
                    U4 q[16];
                    const u64* b0 = Xp;
                    const u64* b1 = Xp + 512;
                    const u64* b2 = Xp + 1024;
                    const u64* b3 = Xp + 1536;
                    int guard = 0;
                    for (;;) {
                        asm volatile(
                            "buffer_inv sc0\n\t"
                            "global_load_dwordx4 %0,  %16, off\n\t"
                            "global_load_dwordx4 %1,  %16, off offset:16\n\t"
                            "global_load_dwordx4 %2,  %16, off offset:2048\n\t"
                            "global_load_dwordx4 %3,  %16, off offset:2064\n\t"
                            "global_load_dwordx4 %4,  %17, off\n\t"
                            "global_load_dwordx4 %5,  %17, off offset:16\n\t"
                            "global_load_dwordx4 %6,  %17, off offset:2048\n\t"
                            "global_load_dwordx4 %7,  %17, off offset:2064\n\t"
                            "global_load_dwordx4 %8,  %18, off\n\t"
                            "global_load_dwordx4 %9,  %18, off offset:16\n\t"
                            "global_load_dwordx4 %10, %18, off offset:2048\n\t"
                            "global_load_dwordx4 %11, %18, off offset:2064\n\t"
                            "global_load_dwordx4 %12, %19, off\n\t"
                            "global_load_dwordx4 %13, %19, off offset:16\n\t"
                            "global_load_dwordx4 %14, %19, off offset:2048\n\t"
                            "global_load_dwordx4 %15, %19, off offset:2064\n\t"
                            "s_waitcnt vmcnt(0)"
                            : "=&v"(q[0].v), "=&v"(q[1].v), "=&v"(q[2].v), "=&v"(q[3].v),
                              "=&v"(q[4].v), "=&v"(q[5].v), "=&v"(q[6].v), "=&v"(q[7].v),
                              "=&v"(q[8].v), "=&v"(q[9].v), "=&v"(q[10].v), "=&v"(q[11].v),
                              "=&v"(q[12].v), "=&v"(q[13].v), "=&v"(q[14].v), "=&v"(q[15].v)
                            : "v"(b0), "v"(b1), "v"(b2), "v"(b3)
                            : "memory");
                        bool ok = true;
#pragma unroll
                        for (int i = 0; i < 16; ++i)
                            ok &= (q[i].u[1] == tag) & (q[i].u[3] == tag);
                        if (ok) break;
                        if ((++guard & 255) == 0) {
                            if (guard > (1 << 18) || aflag(abortFlag)) { sflag(abortFlag); break; }
                        }
                    }
#pragma unroll
                    for (int kc = 0; kc < 8; ++kc) {
                        afr[kc].u[0] = q[kc * 2].u[0];
                        afr[kc].u[1] = q[kc * 2].u[2];
                        afr[kc].u[2] = q[kc * 2 + 1].u[0];
                        afr[kc].u[3] = q[kc * 2 + 1].u[2];
                    }
                } else {
                    // fallback: proven agent-scope path
                    u64 v[32];
                    int guard = 0;
                    for (;;) {
#pragma unroll
                        for (int kc = 0; kc < 8; ++kc)
#pragma unroll
                            for (int p = 0; p < 4; ++p)
                                v[kc * 4 + p] = aload(Xp + (size_t)kc * 256 + p);
                        bool ok = true;
#pragma unroll
                        for (int i = 0; i < 32; ++i) ok &= ((unsigned)(v[i] >> 32) == tag);
                        if (ok) break;
                        if ((++guard & 255) == 0) {
                            if (guard > (1 << 18) || aflag(abortFlag)) { sflag(abortFlag); break; }
                        }
                    }
#pragma unroll
                    for (int kc = 0; kc < 8; ++kc)
#pragma unroll
                        for (int p = 0; p < 4; ++p) afr[kc].u[p] = (unsigned)v[kc * 4 + p];
                }
                // prefetch t+1 now; flies under the MFMA + gates + stores below
                issuePF(t + 1 < SS ? t + 1 : t);
                acc0 = __builtin_amdgcn_mfma_f32_16x16x32_f16(afr[0].v, bfr[0].v, acc0, 0, 0, 0);
                acc1 = __builtin_amdgcn_mfma_f32_16x16x32_f16(afr[1].v, bfr[1].v, acc1, 0, 0, 0);
                acc0 = __builtin_amdgcn_mfma_f32_16x16x32_f16(afr[2].v, bfr[2].v, acc0, 0, 0, 0);
                acc1 = __builtin_amdgcn_mfma_f32_16x16x32_f16(afr[3].v, bfr[3].v, acc1, 0, 0, 0);
                acc0 = __builtin_amdgcn_mfma_f32_16x16x32_f16(afr[4].v, bfr[4].v, acc0, 0, 0, 0);
                acc1 = __builtin_amdgcn_mfma_f32_16x16x32_f16(afr[5].v, bfr[5].v, acc1, 0, 0, 0);
                acc0 = __builtin_amdgcn_mfma_f32_16x16x32_f16(afr[6].v, bfr[6].v, acc0, 0, 0, 0);
                acc1 = __builtin_amdgcn_mfma_f32_16x16x32_f16(afr[7].v, bfr[7].v, acc1, 0, 0, 0);
            } else {
                issuePF(1);
            }
            // early progress post: safe only AFTER the X-poll (poll-exit implies
            // every WG published tag t, hence finished acquire(t-1)); margins
            // +2/+3 keep slots t and t+1 protected for all (incl. lagging) waves
            if (g == 0 && tid == 0) pstore(prog + l, (unsigned)(t + 1));
            f32x4 acc = acc0 + acc1;
            const int par = t & 1;
#pragma unroll
            for (int r = 0; r < 4; ++r) gbuf[par][w][quad * 4 + r][mm] = acc[r];
            __syncthreads();
            // ---- gates ----
            float gi = gbuf[par][0][sb][sd] + gxi;
            float gf = gbuf[par][1][sb][sd] + gxf;
            float gz = gbuf[par][2][sb][sd] + gxz;
            float go = gbuf[par][3][sb][sd] + gxoo;
            float mn = fmaxf(gf + m_, gi);
            float ip = __expf(gi - mn);
            float fp = __expf(gf + m_ - mn);
            float e2z = __expf(2.f * gz);
            float th = 1.f - 2.f * __builtin_amdgcn_rcpf(e2z + 1.f);
            c_ = fp * c_ + ip * th;
            n_ = fp * n_ + ip;
            m_ = mn;
            float sg = __builtin_amdgcn_rcpf(1.f + __expf(-go));
            float hval = sg * c_ * __builtin_amdgcn_rcpf(fmaxf(fabsf(n_), 1.f));
            float rnew = hin + hval;
            // ---- publish h_s(t) FIRST: peers unblock before R-gate/store ----
            // (safe: poll-exit invariant guarantees all peers are done reading
            //  the parity slot being overwritten, independent of position here)
            float hodd = __shfl_down(hval, 1);
            if (doPub) {
                unsigned payload = (unsigned)f16b(hval) | ((unsigned)f16b(hodd) << 16);
                u64 pv = ((u64)tagT << 32) | (u64)payload;
                u64* dst = Xl + (size_t)((t + 1) & 1) * 2048 + pubIdx;
                if (fastX) wgstore(dst, pv);   // write-through into XCD-local L2
                else astore(dst, pv);
            }
            // ---- residual out (now off the inter-WG critical chain) ----
            if (l == 3) {
                hrow[(size_t)t * DD] = rnew;
            } else {
                if (t >= PRD) {  // slot-reuse gate, cached (counters monotone)
                    unsigned needT = (unsigned)(t - PRD);
                    if (!((psC >= needT + 2) & (minPgC >= needT + 1))) {
                        int guard = 0;
                        for (;;) {
                            unsigned a  = pload(psP);       // parallel loads:
                            unsigned b0 = pload(pgP + 0);   // no && short-circuit
                            unsigned b1 = pload(pgP + 1);
                            unsigned b2 = pload(pgP + 2);
                            unsigned b3 = pload(pgP + 3);
                            unsigned mn4 = umin2(umin2(b0, b1), umin2(b2, b3));
                            psC = a; minPgC = mn4;          // update caches
                            if ((a >= needT + 2) & (mn4 >= needT + 1)) break;
                            if (spinBail(guard, abortFlag)) break;
                        }
                    }
                }
                astore(Rcur + (size_t)(t & (PRD - 1)) * 4096 + rIdx,
                       ((u64)tagT << 32) | (u64)__float_as_uint(rnew));
            }
            __syncthreads();
        }
    } else {
        // ================= HELPER ROLE: streaming gx GEMM =================
        const int j = ksl;
        const int w = tid >> 6, lane = tid & 63;
        const int mm = lane & 15, quad = lane >> 4;
        const int hb_ = tid >> 4, hd0 = (tid & 15) * 16;
        unsigned short (*hA)[264] = (unsigned short (*)[264])smemBlob;

        const u64* Rin = Rbuf + (size_t)(l > 0 ? l - 1 : 0) * PRD * 4096;
        u64* GXl = GXbuf + (size_t)l * PGD * 16384;
        const unsigned short* WxL = Wxh + (size_t)l * 262144;
        const float* lngL = lng + l * DD;
        const float* lnbL = lnb + l * DD;
        const float* bgL = bgp + (size_t)l * ND4;
        unsigned* myProg = prog + 4 + l * 4 + j;
        const unsigned* scanProg = prog + l;
        unsigned spC = 0;  // cached lower bound of scan progress

        for (int t = j; t < SS; t += HLP) {
            const unsigned tagT = (unsigned)(t + 1);
            // ---- 1. acquire r[l-1][t] (or embed for l==0) ----
            float rv[16];
            if (l == 0) {
                const float4* p = (const float4*)(hemb + ((size_t)hb_ * SS + t) * DD + hd0);
#pragma unroll
                for (int q4 = 0; q4 < 4; ++q4) {
                    float4 f = p[q4];
                    rv[q4 * 4 + 0] = f.x; rv[q4 * 4 + 1] = f.y;
                    rv[q4 * 4 + 2] = f.z; rv[q4 * 4 + 3] = f.w;
                }
            } else {
                const u64* Rp = Rin + (size_t)(t & (PRD - 1)) * 4096 + (size_t)tid * 16;
                int guard = 0;
                for (;;) {
                    u64 vv[16];
#pragma unroll
                    for (int i = 0; i < 16; ++i) vv[i] = aload(Rp + i);
                    bool ok = true;
#pragma unroll
                    for (int i = 0; i < 16; ++i) ok &= ((unsigned)(vv[i] >> 32) == tagT);
                    if (ok) {
#pragma unroll
                        for (int i = 0; i < 16; ++i) rv[i] = __uint_as_float((unsigned)vv[i]);
                        break;
                    }
                    if (spinBail(guard, abortFlag)) {
#pragma unroll
                        for (int i = 0; i < 16; ++i) rv[i] = 0.f;
                        break;
                    }
                }
            }
            // ---- 2. LN stats (16 threads per batch, shfl-xor reduce) ----
            float s = 0.f, ssq = 0.f;
#pragma unroll
            for (int i = 0; i < 16; ++i) { s += rv[i]; ssq += rv[i] * rv[i]; }
#pragma unroll
            for (int msk = 1; msk < 16; msk <<= 1) {
                s += __shfl_xor(s, msk);
                ssq += __shfl_xor(ssq, msk);
            }
            float muv = s * (1.f / 256.f);
            float rsv = rsqrtf(fmaxf(ssq * (1.f / 256.f) - muv * muv, 0.f) + 1e-5f);
            // ---- 3. LN -> fp16 -> LDS (A-matrix rows = batches) ----
            {
                __align__(16) unsigned short ov[16];
#pragma unroll
                for (int i = 0; i < 16; ++i)
                    ov[i] = f16b((rv[i] - muv) * rsv * lngL[hd0 + i] + lnbL[hd0 + i]);
                *(uint4*)&hA[hb_][hd0] = *(uint4*)&ov[0];
                *(uint4*)&hA[hb_][hd0 + 8] = *(uint4*)&ov[8];
            }
            __syncthreads();
            // early post: this sync covers every thread's R-read for token t;
            // myProg's only consumer semantic is "R[l-1][t] consumed"
            if (tid == 0) pstore(myProg, (unsigned)(t + 1));
            // ---- 4. A-frags from LDS ----
            H8 A[8];
#pragma unroll
            for (int kc = 0; kc < 8; ++kc)
                A[kc].q = *(const uint4*)&hA[mm][kc * 32 + quad * 8];
            // ---- 5. 16 tiles x 8 chunks MFMA, B streamed from L2 ----
            f32x4 acc[16];
            const unsigned short* WxW = WxL + (size_t)w * 16 * 4096;
#pragma unroll
            for (int n = 0; n < 16; ++n) {
                const unsigned short* bp = WxW + (size_t)n * 4096 + (size_t)lane * 8;
                f32x4 a = {0.f, 0.f, 0.f, 0.f};
#pragma unroll
                for (int kc = 0; kc < 8; ++kc) {
                    H8 B;
                    B.q = *(const uint4*)(bp + (size_t)kc * 512);
                    a = __builtin_amdgcn_mfma_f32_16x16x32_f16(A[kc].v, B.v, a, 0, 0, 0);
                }
                acc[n] = a;
            }
            // ---- 6. slot-reuse gate (cached), then write GX ----
            if (t >= PGD) {
                unsigned need = (unsigned)(t - PGD) + 2;
                if (spC < need) {
                    int guard = 0;
                    for (;;) {
                        unsigned v = pload(scanProg);
                        spC = v;
                        if (v >= need) break;
                        if (spinBail(guard, abortFlag)) break;
                    }
                }
            }
            u64* Gq = GXl + (size_t)(t & (PGD - 1)) * 16384;
#pragma unroll
            for (int n = 0; n < 16; ++n) {
                int c = (w * 16 + n) * 16 + mm;
                float bgv = bgL[c];
                f32x4 a = acc[n];
#pragma unroll
                for (int r = 0; r < 4; ++r)
                    astore(Gq + (size_t)(quad * 4 + r) * 1024 + c,
                           ((u64)tagT << 32) | (u64)__float_as_uint(a[r] + bgv));
            }
            __syncthreads();  // covers hA WAR for next token
        }
    }
}

// ---------------------------------------------------------------------------
// final: out[b] = r3[b][S-1][:] . fc_W + fc_b
// ---------------------------------------------------------------------------
__global__ void final_kernel(const float* __restrict__ h, const float* __restrict__ fcW,
                             const float* __restrict__ fcb, float* __restrict__ out) {
    int b = blockIdx.x, lane = threadIdx.x;
    const float4 hv = *(const float4*)(h + ((size_t)b * SS + (SS - 1)) * DD + lane * 4);
    const float4 wv = *(const float4*)(fcW + lane * 4);
    float s = hv.x * wv.x + hv.y * wv.y + hv.z * wv.z + hv.w * wv.w;
#pragma unroll
    for (int off = 32; off; off >>= 1) s += __shfl_down(s, off);
    if (lane == 0) out[b] = s + fcb[0];
}

// ---------------------------------------------------------------------------
extern "C" void kernel_launch(void* const* d_in, const int* in_sizes, int n_in,
                              void* d_out, int out_size, void* d_ws, size_t ws_size,
                              hipStream_t stream) {
    const float* x   = (const float*)d_in[0];
    const float* tf  = (const float*)d_in[1];
    const float* inW = (const float*)d_in[2];
    const float* inb = (const float*)d_in[3];
    const float* lng = (const float*)d_in[4];
    const float* lnb = (const float*)d_in[5];
    const float* Wx  = (const float*)d_in[6];
    const float* Wh  = (const float*)d_in[7];
    const float* bg  = (const float*)d_in[8];
    const float* fcW = (const float*)d_in[9];
    const float* fcb = (const float*)d_in[10];
    float* out = (float*)d_out;

    const size_t nTok = (size_t)BB * SS;
    float* hemb = (float*)d_ws;                                   // 8,388,608 f
    float* hout = hemb + nTok * DD;                               // 8,388,608 f
    unsigned short* Wxh = (unsigned short*)(hout + nTok * DD);    // 1,048,576 us
    u64* Xbuf = (u64*)(Wxh + 1048576);                            // 4*2*2048
    u64* Rbuf = Xbuf + 4 * 2 * 2048;                              // 3*16*4096
    u64* GXbuf = Rbuf + 3 * PRD * 4096;                           // 4*8*16384
    // prog area: [0..19]=prog, [20]=abort, [24..31]=test words (u64 x4),
    // [32..95]=xccTab, [96..159]=ready, [160..223]=result
    unsigned* prog = (unsigned*)(GXbuf + 4 * PGD * 16384);
    int* abortFlag = (int*)(prog + 20);

    const size_t needed = (size_t)((char*)(prog + 256) - (char*)d_ws);
    if (ws_size < needed) return;  // fail visibly instead of corrupting

    hipMemsetAsync(prog, 0, 256 * sizeof(unsigned), stream);
    // X/R/GX need no init: 0xAA poison never matches a tag in [1,2048]

    embed_kernel<<<nTok, DD, 0, stream>>>(x, tf, inW, inb, hemb);
    wxprep_kernel<<<4 * 64, 64, 0, stream>>>(Wx, Wxh);
    mega_kernel<<<128, 256, 0, stream>>>(hemb, Wh, lng, lnb, bg, Wxh, hout,
                                         Xbuf, Rbuf, GXbuf, prog, abortFlag);
    final_kernel<<<BB, 64, 0, stream>>>(hout, fcW, fcb, out);
    (void)in_sizes; (void)n_in; (void)out_size;
}